// Round 8
// baseline (62.777 us; speedup 1.0000x reference)
//
#include <hip/hip_runtime.h>
#include <hip/hip_bf16.h>
#include <math.h>

#define NROW 4096
#define DIM  512
#define TINV8 0.0390625f   // 10/256: features scaled by 16 before fp8, sim scaled by 256
#define EPSN 1e-8f
#define BT 64                       // tile side
#define NB (NROW / BT)              // 64 tiles per side
#define NBLK (NB * (NB + 1) / 2)    // 2080 upper-triangle blocks
#define SLOTS (2 * NB)              // 128 partial-sum slots per row

typedef float f32x4 __attribute__((ext_vector_type(4)));

__device__ __forceinline__ void gload_lds16(const void* g, void* l) {
    __builtin_amdgcn_global_load_lds(
        (const __attribute__((address_space(1))) unsigned int*)g,
        (__attribute__((address_space(3))) unsigned int*)l,
        16, 0, 0);
}

// Kernel 1: blocks 0..1023 row-normalize fp32 -> fp8 e4m3 (x16 scale);
// block 1024 computes per-row targets and zeroes the kloss done-counter.
__global__ __launch_bounds__(256) void kprep(const float* __restrict__ feat,
                                             const int* __restrict__ labels,
                                             unsigned char* __restrict__ fb8,
                                             int* __restrict__ target,
                                             int* __restrict__ donecnt) {
    if (blockIdx.x < NROW / 4) {
        const int row  = blockIdx.x * 4 + (threadIdx.x >> 6);
        const int lane = threadIdx.x & 63;
        const float* rp = feat + (size_t)row * DIM + lane * 8;
        float4 v0 = *(const float4*)rp;
        float4 v1 = *(const float4*)(rp + 4);
        float ss = v0.x*v0.x + v0.y*v0.y + v0.z*v0.z + v0.w*v0.w
                 + v1.x*v1.x + v1.y*v1.y + v1.z*v1.z + v1.w*v1.w;
        #pragma unroll
        for (int m = 1; m < 64; m <<= 1) ss += __shfl_xor(ss, m);
        const float inv = 16.0f / fmaxf(sqrtf(ss), EPSN);
        int w0 = __builtin_amdgcn_cvt_pk_fp8_f32(v0.x * inv, v0.y * inv, 0, false);
        w0     = __builtin_amdgcn_cvt_pk_fp8_f32(v0.z * inv, v0.w * inv, w0, true);
        int w1 = __builtin_amdgcn_cvt_pk_fp8_f32(v1.x * inv, v1.y * inv, 0, false);
        w1     = __builtin_amdgcn_cvt_pk_fp8_f32(v1.z * inv, v1.w * inv, w1, true);
        *(int2*)(fb8 + (size_t)row * DIM + lane * 8) = make_int2(w0, w1);
    } else {
        __shared__ int firstS[16], secondS[16];
        const int t = threadIdx.x;
        if (t < 16) { firstS[t] = NROW; secondS[t] = NROW; }
        if (t == 0)
            __hip_atomic_store(donecnt, 0, __ATOMIC_RELAXED, __HIP_MEMORY_SCOPE_AGENT);
        __syncthreads();
        for (int i = t; i < NROW; i += 256) atomicMin(&firstS[labels[i]], i);
        __syncthreads();
        for (int i = t; i < NROW; i += 256) {
            const int c = labels[i];
            if (i != firstS[c]) atomicMin(&secondS[c], i);
        }
        __syncthreads();
        for (int i = t; i < NROW; i += 256) {
            const int c = labels[i];
            int tg = (firstS[c] == i) ? secondS[c] : firstS[c];
            if (tg >= NROW) tg = (i == 0) ? 1 : 0;  // no-positive: first dropped column
            target[i] = tg;
        }
    }
}

// Kernel 2: IDENTICAL to round 7. Launched TWICE this round (idempotent:
// plain stores of identical values, no atomics) purely to measure its
// duration via the total-time delta, since rocprof top-5 is masked by
// the harness poison-fills.
__global__ __launch_bounds__(256, 8) void ksim(const unsigned char* __restrict__ fb8,
                                               const int* __restrict__ target,
                                               float* __restrict__ tlog,
                                               float* __restrict__ psums) {
    __shared__ __align__(16) unsigned char As[2][BT * 64];  // 4 KB per buffer
    __shared__ __align__(16) unsigned char Bs[2][BT * 64];

    // triangular decode via closed form + correction
    const int idx = blockIdx.x;
    int bi = (int)((129.0f - sqrtf(16641.0f - 8.0f * (float)idx)) * 0.5f);
    #define TRIOFF(b) ((b) * (129 - (b)) / 2)
    while (TRIOFF(bi + 1) <= idx) ++bi;
    while (TRIOFF(bi) > idx) --bi;
    const int bj = bi + (idx - TRIOFF(bi));
    const bool offdiag = (bi != bj);

    const int brow = bi * BT;
    const int bcol = bj * BT;
    const int tid  = threadIdx.x;
    const int wid  = tid >> 6;
    const int lane = tid & 63;
    const int wm = wid >> 1, wn = wid & 1;   // 32x32 quadrant

    f32x4 acc[2][2];
    #pragma unroll
    for (int m = 0; m < 2; m++)
        #pragma unroll
        for (int n = 0; n < 2; n++)
            #pragma unroll
            for (int q = 0; q < 4; q++) acc[m][n][q] = 0.0f;

    // Staging: one 16B gload per thread per matrix; lane -> row lane>>2,
    // chunk lane&3; swizzle key (r&3)^((r>>2)&3) pre-applied to source.
    const int skey = ((lane >> 2) & 3) ^ ((lane >> 4) & 3);
    const int sc   = (lane & 3) ^ skey;
    const int srow = wid * 16 + (lane >> 2);

    auto STAGE = [&](int buf, int kb) {
        const unsigned char* gA = fb8 + (size_t)(brow + srow) * DIM + kb + sc * 16;
        gload_lds16(gA, &As[buf][(wid * 16) * 64]);
        if (offdiag) {
            const unsigned char* gB = fb8 + (size_t)(bcol + srow) * DIM + kb + sc * 16;
            gload_lds16(gB, &Bs[buf][(wid * 16) * 64]);
        }
    };

    const int ro   = lane & 15;
    const int rkey = (ro & 3) ^ ((ro >> 2) & 3);
    const int hp   = (lane >> 4) & 1;   // 8B half within 16B chunk
    const int g2   = lane >> 5;         // chunk LSB from k-octet

    int cur = 0;
    STAGE(cur, 0);
    __syncthreads();

    for (int t = 0; t < DIM / 64; ++t) {
        if (t + 1 < DIM / 64) STAGE(cur ^ 1, (t + 1) * 64);
        const unsigned char* Ab = As[cur];
        const unsigned char* Bb = offdiag ? Bs[cur] : As[cur];
        #pragma unroll
        for (int kk = 0; kk < 2; kk++) {
            const int p   = (kk * 2 + g2) ^ rkey;
            const int cof = (p * 2 + hp) * 8;
            long a[2], b[2];
            #pragma unroll
            for (int m = 0; m < 2; m++)
                a[m] = *(const long*)(Ab + (wm * 32 + m * 16 + ro) * 64 + cof);
            #pragma unroll
            for (int n = 0; n < 2; n++)
                b[n] = *(const long*)(Bb + (wn * 32 + n * 16 + ro) * 64 + cof);
            #pragma unroll
            for (int m = 0; m < 2; m++)
                #pragma unroll
                for (int n = 0; n < 2; n++)
                    acc[m][n] = __builtin_amdgcn_mfma_f32_16x16x32_fp8_fp8(a[m], b[n], acc[m][n], 0, 0, 0);
        }
        __syncthreads();
        cur ^= 1;
    }

    // Epilogue. C/D layout: col = lane&15, row = (lane>>4)*4 + q.
    const int lhi = lane >> 4, llo = lane & 15;
    float colacc[2] = {0.f, 0.f};
    int tgj[2] = {-1, -1};
    if (offdiag) {
        #pragma unroll
        for (int n = 0; n < 2; n++) tgj[n] = target[bcol + wn * 32 + n * 16 + llo];
    }

    #pragma unroll
    for (int m = 0; m < 2; m++) {
        #pragma unroll
        for (int q = 0; q < 4; q++) {
            const int i  = brow + wm * 32 + m * 16 + lhi * 4 + q;
            const int tgi = target[i];
            float psum = 0.0f;
            #pragma unroll
            for (int n = 0; n < 2; n++) {
                const int j = bcol + wn * 32 + n * 16 + llo;
                const float logit = acc[m][n][q] * TINV8;
                const float expv  = __expf(logit);
                if (j != i) psum += expv;             // diagonal excluded exactly
                if (j == tgi) tlog[i] = logit;        // exactly one writer per i
                if (offdiag) {
                    colacc[n] += expv;                // transposed orientation
                    if (i == tgj[n]) tlog[j] = logit;
                }
            }
            psum += __shfl_xor(psum, 1);
            psum += __shfl_xor(psum, 2);
            psum += __shfl_xor(psum, 4);
            psum += __shfl_xor(psum, 8);
            if (llo == 0) psums[(size_t)(2 * bj + wn) * NROW + i] = psum;
        }
    }
    if (offdiag) {
        #pragma unroll
        for (int n = 0; n < 2; n++) {
            colacc[n] += __shfl_xor(colacc[n], 16);
            colacc[n] += __shfl_xor(colacc[n], 32);
            if (lhi == 0)
                psums[(size_t)(2 * bi + wm) * NROW + bcol + wn * 32 + n * 16 + llo] = colacc[n];
        }
    }
}

// Kernel 3: 64 blocks x 64 rows: rowsum_i = sum of 128 psums slots; partial
// loss per block; fenceless last-block finish (R6-validated protocol).
__global__ __launch_bounds__(256) void kloss(const float* __restrict__ psums,
                                             const float* __restrict__ tlog,
                                             float* __restrict__ ploss,
                                             int* __restrict__ donecnt,
                                             float* __restrict__ out) {
    const int tid = threadIdx.x;
    const int r   = tid & 63;
    const int w   = tid >> 6;
    const int brow = blockIdx.x * BT;

    float a = 0.0f;
    for (int s = w; s < SLOTS; s += 4)
        a += psums[(size_t)s * NROW + brow + r];
    __shared__ float red[256];
    red[tid] = a;
    __syncthreads();

    if (tid < 64) {
        const float tot = red[tid] + red[tid + 64] + red[tid + 128] + red[tid + 192];
        float partial = __logf(tot) - tlog[brow + tid];
        #pragma unroll
        for (int m = 1; m < 64; m <<= 1) partial += __shfl_xor(partial, m);
        if (tid == 0)
            __hip_atomic_store(&ploss[blockIdx.x], partial, __ATOMIC_RELAXED, __HIP_MEMORY_SCOPE_AGENT);
    }

    asm volatile("s_waitcnt vmcnt(0)" ::: "memory");
    __shared__ int lastS;
    if (tid == 0)
        lastS = (__hip_atomic_fetch_add(donecnt, 1, __ATOMIC_RELAXED, __HIP_MEMORY_SCOPE_AGENT) == NB - 1);
    __syncthreads();
    if (!lastS) return;

    if (tid < 64) {
        float v = __hip_atomic_load(&ploss[tid], __ATOMIC_RELAXED, __HIP_MEMORY_SCOPE_AGENT);
        #pragma unroll
        for (int m = 1; m < 64; m <<= 1) v += __shfl_xor(v, m);
        if (tid == 0) out[0] = v / (float)NROW;
    }
}

extern "C" void kernel_launch(void* const* d_in, const int* in_sizes, int n_in,
                              void* d_out, int out_size, void* d_ws, size_t ws_size,
                              hipStream_t stream) {
    const float* feat  = (const float*)d_in[0];
    const int* labels  = (const int*)d_in[1];
    float* out = (float*)d_out;

    char* ws = (char*)d_ws;
    unsigned char* fb8 = (unsigned char*)ws;                       // 2 MB
    float* psums  = (float*)(ws + (size_t)NROW * DIM);             // 2 MB (128 x 4096)
    float* tlog   = (float*)(ws + 2 * (size_t)NROW * DIM);         // 16 KB
    int*   target = (int*)(tlog + NROW);                           // 16 KB
    float* ploss  = (float*)(target + NROW);                       // 256 B
    int*   donecnt = (int*)(ploss + NB);                           // 4 B

    kprep<<<NROW / 4 + 1, 256, 0, stream>>>(feat, labels, fb8, target, donecnt);
    // MEASUREMENT: ksim launched twice (idempotent). Total-time delta vs
    // round 7 == one ksim duration, immune to the fill-masked profile.
    ksim <<<NBLK, 256, 0, stream>>>(fb8, target, tlog, psums);
    ksim <<<NBLK, 256, 0, stream>>>(fb8, target, tlog, psums);
    kloss<<<NB, 256, 0, stream>>>(psums, tlog, ploss, donecnt, out);
}

// Round 9
// 44.512 us; speedup vs baseline: 1.4103x; 1.4103x over previous
//
#include <hip/hip_runtime.h>
#include <hip/hip_bf16.h>
#include <math.h>

#define NROW 4096
#define DIM  512
#define TINV8 0.0390625f   // 10/256: features scaled by 16 before fp8, sim scaled by 256
#define EPSN 1e-8f
#define BT 64                       // tile side
#define NB (NROW / BT)              // 64 tiles per side
#define NBLK (NB * (NB + 1) / 2)    // 2080 upper-triangle blocks
#define SLOTS (2 * NB)              // 128 partial-sum slots per row

typedef float f32x4 __attribute__((ext_vector_type(4)));

__device__ __forceinline__ void gload_lds16(const void* g, void* l) {
    __builtin_amdgcn_global_load_lds(
        (const __attribute__((address_space(1))) unsigned int*)g,
        (__attribute__((address_space(3))) unsigned int*)l,
        16, 0, 0);
}

// Kernel 1: blocks 0..1023 row-normalize fp32 -> fp8 e4m3 (x16 scale);
// block 1024 computes per-row targets and zeroes the kloss done-counter.
__global__ __launch_bounds__(256) void kprep(const float* __restrict__ feat,
                                             const int* __restrict__ labels,
                                             unsigned char* __restrict__ fb8,
                                             int* __restrict__ target,
                                             int* __restrict__ donecnt) {
    if (blockIdx.x < NROW / 4) {
        const int row  = blockIdx.x * 4 + (threadIdx.x >> 6);
        const int lane = threadIdx.x & 63;
        const float* rp = feat + (size_t)row * DIM + lane * 8;
        float4 v0 = *(const float4*)rp;
        float4 v1 = *(const float4*)(rp + 4);
        float ss = v0.x*v0.x + v0.y*v0.y + v0.z*v0.z + v0.w*v0.w
                 + v1.x*v1.x + v1.y*v1.y + v1.z*v1.z + v1.w*v1.w;
        #pragma unroll
        for (int m = 1; m < 64; m <<= 1) ss += __shfl_xor(ss, m);
        const float inv = 16.0f / fmaxf(sqrtf(ss), EPSN);
        int w0 = __builtin_amdgcn_cvt_pk_fp8_f32(v0.x * inv, v0.y * inv, 0, false);
        w0     = __builtin_amdgcn_cvt_pk_fp8_f32(v0.z * inv, v0.w * inv, w0, true);
        int w1 = __builtin_amdgcn_cvt_pk_fp8_f32(v1.x * inv, v1.y * inv, 0, false);
        w1     = __builtin_amdgcn_cvt_pk_fp8_f32(v1.z * inv, v1.w * inv, w1, true);
        *(int2*)(fb8 + (size_t)row * DIM + lane * 8) = make_int2(w0, w1);
    } else {
        __shared__ int firstS[16], secondS[16];
        const int t = threadIdx.x;
        if (t < 16) { firstS[t] = NROW; secondS[t] = NROW; }
        if (t == 0)
            __hip_atomic_store(donecnt, 0, __ATOMIC_RELAXED, __HIP_MEMORY_SCOPE_AGENT);
        __syncthreads();
        for (int i = t; i < NROW; i += 256) atomicMin(&firstS[labels[i]], i);
        __syncthreads();
        for (int i = t; i < NROW; i += 256) {
            const int c = labels[i];
            if (i != firstS[c]) atomicMin(&secondS[c], i);
        }
        __syncthreads();
        for (int i = t; i < NROW; i += 256) {
            const int c = labels[i];
            int tg = (firstS[c] == i) ? secondS[c] : firstS[c];
            if (tg >= NROW) tg = (i == 0) ? 1 : 0;  // no-positive: first dropped column
            target[i] = tg;
        }
    }
}

// Kernel 2: R7 structure with ONE change: counted-vmcnt pipeline (T4).
// Raw s_barrier instead of __syncthreads; wait vmcnt(2) (current tile's
// loads done, next tile's 2 stay in flight) instead of the full vmcnt(0)
// drain the compiler emits for __syncthreads. lgkmcnt(0) before the
// trailing barrier guarantees read-before-overwrite across waves.
__global__ __launch_bounds__(256, 8) void ksim(const unsigned char* __restrict__ fb8,
                                               const int* __restrict__ target,
                                               float* __restrict__ tlog,
                                               float* __restrict__ psums) {
    __shared__ __align__(16) unsigned char As[2][BT * 64];  // 4 KB per buffer
    __shared__ __align__(16) unsigned char Bs[2][BT * 64];

    // triangular decode via closed form + correction
    const int idx = blockIdx.x;
    int bi = (int)((129.0f - sqrtf(16641.0f - 8.0f * (float)idx)) * 0.5f);
    #define TRIOFF(b) ((b) * (129 - (b)) / 2)
    while (TRIOFF(bi + 1) <= idx) ++bi;
    while (TRIOFF(bi) > idx) --bi;
    const int bj = bi + (idx - TRIOFF(bi));
    const bool offdiag = (bi != bj);

    const int brow = bi * BT;
    const int bcol = bj * BT;
    const int tid  = threadIdx.x;
    const int wid  = tid >> 6;
    const int lane = tid & 63;
    const int wm = wid >> 1, wn = wid & 1;   // 32x32 quadrant

    f32x4 acc[2][2];
    #pragma unroll
    for (int m = 0; m < 2; m++)
        #pragma unroll
        for (int n = 0; n < 2; n++)
            #pragma unroll
            for (int q = 0; q < 4; q++) acc[m][n][q] = 0.0f;

    // Staging: one 16B gload per thread per matrix; lane -> row lane>>2,
    // chunk lane&3; swizzle key (r&3)^((r>>2)&3) pre-applied to source.
    const int skey = ((lane >> 2) & 3) ^ ((lane >> 4) & 3);
    const int sc   = (lane & 3) ^ skey;
    const int srow = wid * 16 + (lane >> 2);

    auto STAGE = [&](int buf, int kb) {
        const unsigned char* gA = fb8 + (size_t)(brow + srow) * DIM + kb + sc * 16;
        gload_lds16(gA, &As[buf][(wid * 16) * 64]);
        if (offdiag) {
            const unsigned char* gB = fb8 + (size_t)(bcol + srow) * DIM + kb + sc * 16;
            gload_lds16(gB, &Bs[buf][(wid * 16) * 64]);
        }
    };

    const int ro   = lane & 15;
    const int rkey = (ro & 3) ^ ((ro >> 2) & 3);
    const int hp   = (lane >> 4) & 1;   // 8B half within 16B chunk
    const int g2   = lane >> 5;         // chunk LSB from k-octet

    int cur = 0;
    STAGE(cur, 0);

    for (int t = 0; t < DIM / 64; ++t) {
        if (t + 1 < DIM / 64) {
            STAGE(cur ^ 1, (t + 1) * 64);
            // current tile's loads done; next tile's stay in flight
            if (offdiag) asm volatile("s_waitcnt vmcnt(2)" ::: "memory");
            else         asm volatile("s_waitcnt vmcnt(1)" ::: "memory");
        } else {
            asm volatile("s_waitcnt vmcnt(0)" ::: "memory");
        }
        asm volatile("s_barrier" ::: "memory");

        const unsigned char* Ab = As[cur];
        const unsigned char* Bb = offdiag ? Bs[cur] : As[cur];
        #pragma unroll
        for (int kk = 0; kk < 2; kk++) {
            const int p   = (kk * 2 + g2) ^ rkey;
            const int cof = (p * 2 + hp) * 8;
            long a[2], b[2];
            #pragma unroll
            for (int m = 0; m < 2; m++)
                a[m] = *(const long*)(Ab + (wm * 32 + m * 16 + ro) * 64 + cof);
            #pragma unroll
            for (int n = 0; n < 2; n++)
                b[n] = *(const long*)(Bb + (wn * 32 + n * 16 + ro) * 64 + cof);
            #pragma unroll
            for (int m = 0; m < 2; m++)
                #pragma unroll
                for (int n = 0; n < 2; n++)
                    acc[m][n] = __builtin_amdgcn_mfma_f32_16x16x32_fp8_fp8(a[m], b[n], acc[m][n], 0, 0, 0);
        }
        // all this wave's ds_reads returned; then barrier -> safe to overwrite
        asm volatile("s_waitcnt lgkmcnt(0)" ::: "memory");
        asm volatile("s_barrier" ::: "memory");
        cur ^= 1;
    }

    // Epilogue. C/D layout: col = lane&15, row = (lane>>4)*4 + q.
    const int lhi = lane >> 4, llo = lane & 15;
    float colacc[2] = {0.f, 0.f};
    int tgj[2] = {-1, -1};
    if (offdiag) {
        #pragma unroll
        for (int n = 0; n < 2; n++) tgj[n] = target[bcol + wn * 32 + n * 16 + llo];
    }

    #pragma unroll
    for (int m = 0; m < 2; m++) {
        #pragma unroll
        for (int q = 0; q < 4; q++) {
            const int i  = brow + wm * 32 + m * 16 + lhi * 4 + q;
            const int tgi = target[i];
            float psum = 0.0f;
            #pragma unroll
            for (int n = 0; n < 2; n++) {
                const int j = bcol + wn * 32 + n * 16 + llo;
                const float logit = acc[m][n][q] * TINV8;
                const float expv  = __expf(logit);
                if (j != i) psum += expv;             // diagonal excluded exactly
                if (j == tgi) tlog[i] = logit;        // exactly one writer per i
                if (offdiag) {
                    colacc[n] += expv;                // transposed orientation
                    if (i == tgj[n]) tlog[j] = logit;
                }
            }
            psum += __shfl_xor(psum, 1);
            psum += __shfl_xor(psum, 2);
            psum += __shfl_xor(psum, 4);
            psum += __shfl_xor(psum, 8);
            if (llo == 0) psums[(size_t)(2 * bj + wn) * NROW + i] = psum;
        }
    }
    if (offdiag) {
        #pragma unroll
        for (int n = 0; n < 2; n++) {
            colacc[n] += __shfl_xor(colacc[n], 16);
            colacc[n] += __shfl_xor(colacc[n], 32);
            if (lhi == 0)
                psums[(size_t)(2 * bi + wm) * NROW + bcol + wn * 32 + n * 16 + llo] = colacc[n];
        }
    }
}

// Kernel 3: 64 blocks x 64 rows: rowsum_i = sum of 128 psums slots; partial
// loss per block; fenceless last-block finish (R6-validated protocol).
__global__ __launch_bounds__(256) void kloss(const float* __restrict__ psums,
                                             const float* __restrict__ tlog,
                                             float* __restrict__ ploss,
                                             int* __restrict__ donecnt,
                                             float* __restrict__ out) {
    const int tid = threadIdx.x;
    const int r   = tid & 63;
    const int w   = tid >> 6;
    const int brow = blockIdx.x * BT;

    float a = 0.0f;
    for (int s = w; s < SLOTS; s += 4)
        a += psums[(size_t)s * NROW + brow + r];
    __shared__ float red[256];
    red[tid] = a;
    __syncthreads();

    if (tid < 64) {
        const float tot = red[tid] + red[tid + 64] + red[tid + 128] + red[tid + 192];
        float partial = __logf(tot) - tlog[brow + tid];
        #pragma unroll
        for (int m = 1; m < 64; m <<= 1) partial += __shfl_xor(partial, m);
        if (tid == 0)
            __hip_atomic_store(&ploss[blockIdx.x], partial, __ATOMIC_RELAXED, __HIP_MEMORY_SCOPE_AGENT);
    }

    asm volatile("s_waitcnt vmcnt(0)" ::: "memory");
    __shared__ int lastS;
    if (tid == 0)
        lastS = (__hip_atomic_fetch_add(donecnt, 1, __ATOMIC_RELAXED, __HIP_MEMORY_SCOPE_AGENT) == NB - 1);
    __syncthreads();
    if (!lastS) return;

    if (tid < 64) {
        float v = __hip_atomic_load(&ploss[tid], __ATOMIC_RELAXED, __HIP_MEMORY_SCOPE_AGENT);
        #pragma unroll
        for (int m = 1; m < 64; m <<= 1) v += __shfl_xor(v, m);
        if (tid == 0) out[0] = v / (float)NROW;
    }
}

extern "C" void kernel_launch(void* const* d_in, const int* in_sizes, int n_in,
                              void* d_out, int out_size, void* d_ws, size_t ws_size,
                              hipStream_t stream) {
    const float* feat  = (const float*)d_in[0];
    const int* labels  = (const int*)d_in[1];
    float* out = (float*)d_out;

    char* ws = (char*)d_ws;
    unsigned char* fb8 = (unsigned char*)ws;                       // 2 MB
    float* psums  = (float*)(ws + (size_t)NROW * DIM);             // 2 MB (128 x 4096)
    float* tlog   = (float*)(ws + 2 * (size_t)NROW * DIM);         // 16 KB
    int*   target = (int*)(tlog + NROW);                           // 16 KB
    float* ploss  = (float*)(target + NROW);                       // 256 B
    int*   donecnt = (int*)(ploss + NB);                           // 4 B

    kprep<<<NROW / 4 + 1, 256, 0, stream>>>(feat, labels, fb8, target, donecnt);
    ksim <<<NBLK, 256, 0, stream>>>(fb8, target, tlog, psums);
    kloss<<<NB, 256, 0, stream>>>(psums, tlog, ploss, donecnt, out);
}